// Round 2
// baseline (7788.687 us; speedup 1.0000x reference)
//
#include <hip/hip_runtime.h>
#include <hip/hip_bf16.h>

// Problem constants
#define B_ 2048
#define L_ 107
#define E_ 128
#define H_ 128
#define PRED_ 68
#define M_ (B_*L_)   // 219136 rows

typedef __bf16 bf16;
typedef __bf16 bf16x8 __attribute__((ext_vector_type(8)));
typedef float f32x4 __attribute__((ext_vector_type(4)));

__device__ __forceinline__ void gload16(const void* g, void* l) {
  __builtin_amdgcn_global_load_lds(
      (const __attribute__((address_space(1))) unsigned int*)g,
      (__attribute__((address_space(3))) unsigned int*)l, 16, 0, 0);
}

__device__ __forceinline__ float sigm(float x)  { return 1.f / (1.f + __expf(-x)); }
__device__ __forceinline__ float tanhx(float x) { return 1.f - 2.f / (1.f + __expf(2.f * x)); }

// ---------------- pack kernels ----------------
// wih pack: [gl(9)][kt(12)][nb(6)][nt(8)][lane(64)][e(8)]  (B-fragment-linear, value = Wih[n][k])
__global__ void pack_wih_k(const float* __restrict__ w_ih, bf16* __restrict__ out) {
  int idx = blockIdx.x * 256 + threadIdx.x;
  if (idx >= 9*12*6*8*64*8) return;
  int e = idx & 7;
  int lane = (idx >> 3) & 63;
  int q = idx >> 9;
  int nt = q & 7; q >>= 3;
  int nb = q % 6; q /= 6;
  int kt = q % 12; int gl = q / 12;
  int ng = nb*128 + nt*16 + (lane & 15);     // 0..767 : [dir0 384 | dir1 384]
  int k  = kt*32 + (lane >> 4)*8 + e;        // 0..383
  int d  = (ng >= 384) ? 1 : 0;
  int np = ng - d*384;
  float v = w_ih[(((size_t)(gl*2 + d)*384 + np)*384 + k)];
  out[idx] = (bf16)v;
}

// whh pack: [gl(9)][d(2)][ks(4)][nt(24)][lane(64)][e(8)]  (value = Whh[n][k])
__global__ void pack_whh_k(const float* __restrict__ w_hh, bf16* __restrict__ out) {
  int idx = blockIdx.x * 256 + threadIdx.x;
  if (idx >= 9*2*4*24*64*8) return;
  int e = idx & 7;
  int lane = (idx >> 3) & 63;
  int q = idx >> 9;
  int nt = q % 24; q /= 24;
  int ks = q & 3;  q >>= 2;
  int d  = q & 1;  int gl = q >> 1;
  int n = nt*16 + (lane & 15);
  int k = ks*32 + (lane >> 4)*8 + e;
  out[idx] = (bf16)w_hh[((size_t)(gl*2 + d)*384 + n)*128 + k];
}

// bias pack: bias[gl][768] = bih + (n<256 ? bhh : 0); bhhn[gl][d][128] = bhh[256+j]
__global__ void pack_bias_k(const float* __restrict__ b_ih, const float* __restrict__ b_hh,
                            float* __restrict__ bias, float* __restrict__ bhhn) {
  int idx = blockIdx.x * 256 + threadIdx.x;
  if (idx < 9*768) {
    int gl = idx / 768; int n = idx % 768;
    int d = (n >= 384) ? 1 : 0; int np = n - d*384;
    float v = b_ih[(gl*2 + d)*384 + np];
    if (np < 256) v += b_hh[(gl*2 + d)*384 + np];
    bias[idx] = v;
  }
  if (idx < 9*256) {
    int gl = idx / 256; int r = idx % 256;
    int d = (r >= 128) ? 1 : 0; int j = r & 127;
    bhhn[idx] = b_hh[(gl*2 + d)*384 + 256 + j];
  }
}

// ---------------- embed ----------------
__global__ void embed_k(const int* __restrict__ seq, const int* __restrict__ str,
                        const int* __restrict__ lp, const float* __restrict__ table,
                        bf16* __restrict__ x0) {
  int idx = blockIdx.x * 256 + threadIdx.x;   // m*48 + q
  if (idx >= M_*48) return;
  int m = idx / 48, q = idx % 48;
  int c = q >> 4; int e0 = (q & 15) * 8;
  int v = (c == 0 ? seq : (c == 1 ? str : lp))[m];
  const float* src = table + v*128 + e0;
  float4 f0 = *(const float4*)(src);
  float4 f1 = *(const float4*)(src + 4);
  bf16x8 o;
  o[0]=(bf16)f0.x; o[1]=(bf16)f0.y; o[2]=(bf16)f0.z; o[3]=(bf16)f0.w;
  o[4]=(bf16)f1.x; o[5]=(bf16)f1.y; o[6]=(bf16)f1.z; o[7]=(bf16)f1.w;
  *reinterpret_cast<bf16x8*>(x0 + (size_t)m*384 + q*8) = o;
}

// ---------------- projection GEMM (128x128 tile, BK=32) ----------------
// C[m][n] = sum_k A[m][k]*Wih[n][k] + bias[n], stored bf16 into xp (stride 768)
// A/xp are chunk-local pointers (row 0 = chunk start).
__global__ __launch_bounds__(256) void gemm_proj_k(const bf16* __restrict__ A, int lda, int KT,
                                                   const bf16* __restrict__ Bp,
                                                   const float* __restrict__ bias,
                                                   bf16* __restrict__ xp) {
  __shared__ __align__(16) bf16 As[128*32];
  __shared__ __align__(16) bf16 Bs[512*8];
  int tid = threadIdx.x; int lane = tid & 63; int w = tid >> 6;
  int l4 = lane & 15, g4 = lane >> 4;
  int wm = w >> 1, wn = w & 1;
  int mb = blockIdx.x, nb = blockIdx.y;
  const bf16* Ab = A + (size_t)mb * 128 * lda;
  const bf16* Bb = Bp + (size_t)nb * 4096;
  f32x4 acc[4][4];
  #pragma unroll
  for (int i = 0; i < 4; ++i)
    #pragma unroll
    for (int j = 0; j < 4; ++j) { f32x4 z = {0.f,0.f,0.f,0.f}; acc[i][j] = z; }

  for (int kt = 0; kt < KT; ++kt) {
    __syncthreads();
    #pragma unroll
    for (int i = 0; i < 2; ++i) {
      int c = tid + 256*i;
      int r = c >> 2, cc = c & 3;
      // A: LDS chunk (r,cc) holds global k-chunk (cc ^ (r&3))  -> bank-conflict-free frag reads
      gload16(Ab + (size_t)r*lda + kt*32 + ((cc ^ (r & 3)) * 8), As + (size_t)c*8);
      gload16(Bb + (size_t)kt*6*4096 + (size_t)c*8, Bs + (size_t)c*8);
    }
    __syncthreads();
    bf16x8 af[4], bfr[4];
    #pragma unroll
    for (int mt = 0; mt < 4; ++mt) {
      int r = wm*64 + mt*16 + l4;
      af[mt] = *reinterpret_cast<const bf16x8*>(As + r*32 + ((g4 ^ (r & 3)) * 8));
    }
    #pragma unroll
    for (int nt = 0; nt < 4; ++nt)
      bfr[nt] = *reinterpret_cast<const bf16x8*>(Bs + ((wn*4 + nt)*64 + lane)*8);
    #pragma unroll
    for (int mt = 0; mt < 4; ++mt)
      #pragma unroll
      for (int nt = 0; nt < 4; ++nt)
        acc[mt][nt] = __builtin_amdgcn_mfma_f32_16x16x32_bf16(af[mt], bfr[nt], acc[mt][nt], 0, 0, 0);
  }
  int m0 = mb*128 + wm*64, n0 = nb*128 + wn*64;
  #pragma unroll
  for (int mt = 0; mt < 4; ++mt)
    #pragma unroll
    for (int nt = 0; nt < 4; ++nt) {
      int col = n0 + nt*16 + l4;
      float bv = bias[col];
      #pragma unroll
      for (int i = 0; i < 4; ++i) {
        int row = m0 + mt*16 + g4*4 + i;
        xp[(size_t)row*768 + col] = (bf16)(acc[mt][nt][i] + bv);
      }
    }
}

// ---------------- GRU scan (one layer, both dirs, one batch chunk) ----------------
// grid (Bc/16, 2): 16 batch rows per block, 4 waves; wave w owns h-cols [32w,32w+32)
// xp is chunk-local; xout is the global activation buffer; bOff = chunk batch offset.
__global__ __launch_bounds__(256, 1) void scan_k(const bf16* __restrict__ xp,
                                                 const bf16* __restrict__ whh,
                                                 const float* __restrict__ bhhn,
                                                 bf16* __restrict__ xout, int bOff) {
  __shared__ __align__(16) bf16 h_lds[2048];   // A-fragment order: [ks(4)][lane(64)][e(8)]
  int tid = threadIdx.x; int lane = tid & 63; int w = tid >> 6;
  int l4 = lane & 15, g4 = lane >> 4;
  int d = blockIdx.y;
  int b0 = blockIdx.x * 16;                    // chunk-local batch base
  int ntl[6];
  ntl[0] = 2*w;    ntl[1] = 2*w + 1;
  ntl[2] = 8+2*w;  ntl[3] = 9+2*w;
  ntl[4] = 16+2*w; ntl[5] = 17+2*w;

  // Whh B-fragments fully in registers (constant over time)
  bf16x8 bw[6][4];
  #pragma unroll
  for (int nt = 0; nt < 6; ++nt)
    #pragma unroll
    for (int ks = 0; ks < 4; ++ks)
      bw[nt][ks] = *reinterpret_cast<const bf16x8*>(whh + ((size_t)(d*4 + ks)*24 + ntl[nt])*512 + lane*8);

  float bn[2];
  bn[0] = bhhn[d*128 + w*32 + l4];
  bn[1] = bhhn[d*128 + w*32 + 16 + l4];
  float h_own[2][4] = {{0,0,0,0},{0,0,0,0}};
  reinterpret_cast<float4*>(h_lds)[tid] = make_float4(0.f, 0.f, 0.f, 0.f);

  bf16 xa[6][4], xb[6][4];
  { // prologue: load xp for t=0
    int tc = d ? 106 : 0;
    #pragma unroll
    for (int nt = 0; nt < 6; ++nt)
      #pragma unroll
      for (int i = 0; i < 4; ++i)
        xa[nt][i] = xp[(size_t)((b0 + g4*4 + i)*107 + tc)*768 + d*384 + ntl[nt]*16 + l4];
  }
  __syncthreads();

  auto step = [&](bf16 (&xu)[6][4], bf16 (&xl)[6][4], int t) {
    int tc = d ? (106 - t) : t;
    int t1 = (t + 1 < 107) ? (t + 1) : 106;
    int tcn = d ? (106 - t1) : t1;
    // A-fragments of h from LDS (fragment-linear, conflict-free)
    bf16x8 a[4];
    #pragma unroll
    for (int ks = 0; ks < 4; ++ks)
      a[ks] = *reinterpret_cast<const bf16x8*>(h_lds + (ks*64 + lane)*8);
    // prefetch next step's xp (latency hidden under MFMA+gates)
    #pragma unroll
    for (int nt = 0; nt < 6; ++nt)
      #pragma unroll
      for (int i = 0; i < 4; ++i)
        xl[nt][i] = xp[(size_t)((b0 + g4*4 + i)*107 + tcn)*768 + d*384 + ntl[nt]*16 + l4];
    // gh = h @ Whh^T
    f32x4 acc[6];
    #pragma unroll
    for (int nt = 0; nt < 6; ++nt) { f32x4 z = {0.f,0.f,0.f,0.f}; acc[nt] = z; }
    #pragma unroll
    for (int ks = 0; ks < 4; ++ks)
      #pragma unroll
      for (int nt = 0; nt < 6; ++nt)
        acc[nt] = __builtin_amdgcn_mfma_f32_16x16x32_bf16(a[ks], bw[nt][ks], acc[nt], 0, 0, 0);
    // gates
    bf16 hb[2][4];
    #pragma unroll
    for (int tau = 0; tau < 2; ++tau)
      #pragma unroll
      for (int i = 0; i < 4; ++i) {
        float xr = (float)xu[tau][i];
        float xz = (float)xu[2 + tau][i];
        float xn = (float)xu[4 + tau][i];
        float r = sigm(xr + acc[tau][i]);          // bih+bhh folded into xp
        float z = sigm(xz + acc[2 + tau][i]);
        float n = tanhx(xn + r * (acc[4 + tau][i] + bn[tau]));  // bhh_n inside r*( )
        float hv = (1.f - z) * n + z * h_own[tau][i];
        h_own[tau][i] = hv;
        hb[tau][i] = (bf16)hv;
      }
    __syncthreads();   // all waves done reading h_lds before overwrite
    #pragma unroll
    for (int tau = 0; tau < 2; ++tau)
      #pragma unroll
      for (int i = 0; i < 4; ++i) {
        int j = w*32 + tau*16 + l4;
        int s = j >> 5, c3 = (j >> 3) & 3, e = j & 7;
        int m = g4*4 + i;
        h_lds[(s*64 + m + 16*c3)*8 + e] = hb[tau][i];
        xout[(size_t)((bOff + b0 + m)*107 + tc)*256 + d*128 + j] = hb[tau][i];
      }
    __syncthreads();   // h writes visible before next step's reads
  };

  for (int t = 0; t < 107; t += 2) {
    step(xa, xb, t);
    if (t + 1 < 107) step(xb, xa, t + 1);
  }
}

// ---------------- final linear ----------------
__global__ void final_k(const bf16* __restrict__ hs, const float* __restrict__ lw,
                        const float* __restrict__ lb, float* __restrict__ out) {
  __shared__ float wsm[768];
  int tid = threadIdx.x;
  for (int i = tid; i < 768; i += 256) wsm[i] = lw[i];
  __syncthreads();
  int idx = blockIdx.x * 256 + tid;           // 0..139263  (b*68 + t)
  int b = idx / 68, t = idx % 68;
  const bf16* row = hs + (size_t)(b*107 + t) * 256;
  float a0 = lb[0], a1 = lb[1], a2 = lb[2];
  for (int j0 = 0; j0 < 256; j0 += 8) {
    bf16x8 v = *reinterpret_cast<const bf16x8*>(row + j0);
    #pragma unroll
    for (int e = 0; e < 8; ++e) {
      float f = (float)v[e];
      a0 += f * wsm[(j0 + e)*3 + 0];
      a1 += f * wsm[(j0 + e)*3 + 1];
      a2 += f * wsm[(j0 + e)*3 + 2];
    }
  }
  out[(size_t)idx*3 + 0] = a0;
  out[(size_t)idx*3 + 1] = a1;
  out[(size_t)idx*3 + 2] = a2;
}

// ---------------- launch ----------------
extern "C" void kernel_launch(void* const* d_in, const int* in_sizes, int n_in,
                              void* d_out, int out_size, void* d_ws, size_t ws_size,
                              hipStream_t stream) {
  const int*   seq   = (const int*)d_in[0];
  const int*   str   = (const int*)d_in[1];
  const int*   lp    = (const int*)d_in[2];
  const float* table = (const float*)d_in[3];
  const float* w_ih  = (const float*)d_in[4];
  const float* w_hh  = (const float*)d_in[5];
  const float* b_ih  = (const float*)d_in[6];
  const float* b_hh  = (const float*)d_in[7];
  const float* lw    = (const float*)d_in[8];
  const float* lb    = (const float*)d_in[9];
  float* out = (float*)d_out;
  char* ws = (char*)d_ws;

  // ---- ws-size-adaptive layout ----
  // X: single activation buffer (widest = layer-0 input, 384 cols bf16).
  //    GEMM reads X -> XP; scan reads XP -> writes 256-wide back over X (X dead).
  // XP: projection buffer for ONE batch chunk (both dirs, 768 cols bf16).
  const size_t xsz   = (size_t)M_ * 384 * 2;        // 168,296,448
  const size_t xpfull= (size_t)M_ * 768 * 2;        // 336,592,896
  const size_t wihsz = 9*12*6*8*64*8 * 2;           // 5,308,416
  const size_t whhsz = 9*2*4*24*64*8 * 2;           // 1,769,472
  const size_t biassz= 9*768*4, bhhnsz = 9*256*4;
  int NC = 1;
  while (NC < 8 && xsz + xpfull/NC + wihsz + whhsz + biassz + bhhnsz > ws_size) NC *= 2;
  const size_t xpsz = xpfull / NC;

  bf16* X   = (bf16*)(ws);
  bf16* XP  = (bf16*)(ws + xsz);
  bf16* WIH = (bf16*)(ws + xsz + xpsz);
  bf16* WHH = (bf16*)(ws + xsz + xpsz + wihsz);
  float* BIAS = (float*)(ws + xsz + xpsz + wihsz + whhsz);
  float* BHHN = (float*)(ws + xsz + xpsz + wihsz + whhsz + biassz);

  hipLaunchKernelGGL(pack_wih_k,  dim3(2654208/256), dim3(256), 0, stream, w_ih, WIH);
  hipLaunchKernelGGL(pack_whh_k,  dim3(884736/256),  dim3(256), 0, stream, w_hh, WHH);
  hipLaunchKernelGGL(pack_bias_k, dim3(27),          dim3(256), 0, stream, b_ih, b_hh, BIAS, BHHN);
  hipLaunchKernelGGL(embed_k,     dim3(M_*48/256),   dim3(256), 0, stream, seq, str, lp, table, X);

  const int Bc = B_ / NC;            // batch rows per chunk
  const int Mc = M_ / NC;            // xp rows per chunk
  int lda = 384, KT = 12;
  for (int gl = 0; gl < 9; ++gl) {
    for (int c = 0; c < NC; ++c) {
      const bf16* Achunk = X + (size_t)c * Mc * lda;   // chunk-contiguous rows
      hipLaunchKernelGGL(gemm_proj_k, dim3(Mc/128, 6), dim3(256), 0, stream,
                         Achunk, lda, KT, WIH + (size_t)gl*294912, BIAS + gl*768, XP);
      hipLaunchKernelGGL(scan_k, dim3(Bc/16, 2), dim3(256), 0, stream,
                         XP, WHH + (size_t)gl*98304, BHHN + gl*256, X, c*Bc);
    }
    lda = 256; KT = 8;
  }
  hipLaunchKernelGGL(final_k, dim3(544), dim3(256), 0, stream, X, lw, lb, out);
}

// Round 4
// 3776.286 us; speedup vs baseline: 2.0625x; 2.0625x over previous
//
#include <hip/hip_runtime.h>
#include <hip/hip_bf16.h>

// Problem constants
#define B_ 2048
#define L_ 107
#define E_ 128
#define H_ 128
#define PRED_ 68
#define M_ (B_*L_)   // 219136 rows

typedef __bf16 bf16;
typedef __bf16 bf16x8 __attribute__((ext_vector_type(8)));
typedef float f32x4 __attribute__((ext_vector_type(4)));

__device__ __forceinline__ void gload16(const void* g, void* l) {
  __builtin_amdgcn_global_load_lds(
      (const __attribute__((address_space(1))) unsigned int*)g,
      (__attribute__((address_space(3))) unsigned int*)l, 16, 0, 0);
}

__device__ __forceinline__ float sigm(float x)  { return 1.f / (1.f + __expf(-x)); }
__device__ __forceinline__ float tanhx(float x) { return 1.f - 2.f / (1.f + __expf(2.f * x)); }

// ---------------- pack kernels ----------------
// wih pack: [gl(9)][kt(12)][nb6(6)][nt(8)][lane(64)][e(8)]  (B-fragment-linear, value = Wih[n][k])
__global__ void pack_wih_k(const float* __restrict__ w_ih, bf16* __restrict__ out) {
  int idx = blockIdx.x * 256 + threadIdx.x;
  if (idx >= 9*12*6*8*64*8) return;
  int e = idx & 7;
  int lane = (idx >> 3) & 63;
  int q = idx >> 9;
  int nt = q & 7; q >>= 3;
  int nb = q % 6; q /= 6;
  int kt = q % 12; int gl = q / 12;
  int ng = nb*128 + nt*16 + (lane & 15);     // 0..767 : [dir0 384 | dir1 384]
  int k  = kt*32 + (lane >> 4)*8 + e;        // 0..383
  int d  = (ng >= 384) ? 1 : 0;
  int np = ng - d*384;
  float v = w_ih[(((size_t)(gl*2 + d)*384 + np)*384 + k)];
  out[idx] = (bf16)v;
}

// whh pack: [gl(9)][d(2)][ks(4)][nt(24)][lane(64)][e(8)]  (value = Whh[n][k])
__global__ void pack_whh_k(const float* __restrict__ w_hh, bf16* __restrict__ out) {
  int idx = blockIdx.x * 256 + threadIdx.x;
  if (idx >= 9*2*4*24*64*8) return;
  int e = idx & 7;
  int lane = (idx >> 3) & 63;
  int q = idx >> 9;
  int nt = q % 24; q /= 24;
  int ks = q & 3;  q >>= 2;
  int d  = q & 1;  int gl = q >> 1;
  int n = nt*16 + (lane & 15);
  int k = ks*32 + (lane >> 4)*8 + e;
  out[idx] = (bf16)w_hh[((size_t)(gl*2 + d)*384 + n)*128 + k];
}

// bias pack: bias[gl][768] = bih + (n<256 ? bhh : 0); bhhn[gl][d][128] = bhh[256+j]
__global__ void pack_bias_k(const float* __restrict__ b_ih, const float* __restrict__ b_hh,
                            float* __restrict__ bias, float* __restrict__ bhhn) {
  int idx = blockIdx.x * 256 + threadIdx.x;
  if (idx < 9*768) {
    int gl = idx / 768; int n = idx % 768;
    int d = (n >= 384) ? 1 : 0; int np = n - d*384;
    float v = b_ih[(gl*2 + d)*384 + np];
    if (np < 256) v += b_hh[(gl*2 + d)*384 + np];
    bias[idx] = v;
  }
  if (idx < 9*256) {
    int gl = idx / 256; int r = idx % 256;
    int d = (r >= 128) ? 1 : 0; int j = r & 127;
    bhhn[idx] = b_hh[(gl*2 + d)*384 + 256 + j];
  }
}

// ---------------- shadow copy (per layer >=1, before phases) ----------------
// SHLO[b][t<54][128]   = X[b][t][0:128]    (fwd halves, read late by bwd GEMM)
// SHHI[b][t-54][128]   = X[b][t][128:256]  (bwd halves, read late by fwd GEMM), t in [54,107)
__global__ void shadow_k(const bf16* __restrict__ X, bf16* __restrict__ shlo,
                         bf16* __restrict__ shhi) {
  int idx = blockIdx.x * 256 + threadIdx.x;      // one 8-elem chunk each
  const int NLO = 2048*54*16;
  if (idx < NLO) {
    int k8 = idx & 15; int q = idx >> 4; int t = q % 54; int b = q / 54;
    *reinterpret_cast<bf16x8*>(shlo + ((size_t)b*54 + t)*128 + k8*8) =
      *reinterpret_cast<const bf16x8*>(X + ((size_t)b*107 + t)*256 + k8*8);
  } else {
    idx -= NLO;
    int k8 = idx & 15; int q = idx >> 4; int t = 54 + q % 53; int b = q / 53;
    if (b < 2048)
      *reinterpret_cast<bf16x8*>(shhi + ((size_t)b*53 + (t-54))*128 + k8*8) =
        *reinterpret_cast<const bf16x8*>(X + ((size_t)b*107 + t)*256 + 128 + k8*8);
  }
}

// ---------------- projection GEMM (time-windowed, embed-fused for layer 0) ----------------
// grid (16*len, 3, 2): mb = m-tile (rows m = b*len+tw), nb = n-tile (128 of 384), z = dir.
// Row m -> (b = m/len, tw = m%len), t = dir ? (t0b - tw) : (t0f + tw).
// Layers>=1: A row cols k<128 from X or SHLO, k>=128 from X or SHHI (alias-safe).
// Layer 0  : A row = concat(table[seq],table[str],table[lp]) from LDS bf16 table.
__global__ __launch_bounds__(256) void gemm_proj_k(
    const bf16* __restrict__ Xin, const bf16* __restrict__ shlo, const bf16* __restrict__ shhi,
    const int* __restrict__ seq, const int* __restrict__ str, const int* __restrict__ lp,
    const float* __restrict__ table, int L0, int KT,
    const bf16* __restrict__ Bp, const float* __restrict__ bias,
    bf16* __restrict__ xpw, int len, int t0f, int t0b) {
  __shared__ __align__(16) bf16 As[128*32];
  __shared__ __align__(16) bf16 Bs[512*8];
  __shared__ __align__(16) bf16 TBl[14*128];
  __shared__ int tokl[3*128];
  int tid = threadIdx.x; int lane = tid & 63; int w = tid >> 6;
  int l4 = lane & 15, g4 = lane >> 4;
  int wm = w >> 1, wn = w & 1;
  int mb = blockIdx.x, nb = blockIdx.y, d = blockIdx.z;

  // per-thread staging rows (2 chunks)
  int c0 = tid, c1 = tid + 256;
  int r0 = c0 >> 2, cc0 = c0 & 3;
  int r1 = c1 >> 2, cc1 = c1 & 3;
  int sw0 = (cc0 ^ (r0 & 3)) * 8, sw1 = (cc1 ^ (r1 & 3)) * 8;
  int m0s = mb*128 + r0; int b0s = m0s / len; int tw0s = m0s - b0s*len;
  int m1s = mb*128 + r1; int b1s = m1s / len; int tw1s = m1s - b1s*len;
  int tA0 = d ? (t0b - tw0s) : (t0f + tw0s);
  int tA1 = d ? (t0b - tw1s) : (t0f + tw1s);
  const bf16* xr0 = Xin + ((size_t)b0s*107 + tA0) * 256;
  const bf16* xr1 = Xin + ((size_t)b1s*107 + tA1) * 256;
  const bf16 *pLo0, *pHi0, *pLo1, *pHi1;
  if (d == 0) {
    pLo0 = xr0; pHi0 = (tA0 < 54) ? xr0 : (shhi + ((size_t)b0s*53 + (tA0-54))*128 - 128);
    pLo1 = xr1; pHi1 = (tA1 < 54) ? xr1 : (shhi + ((size_t)b1s*53 + (tA1-54))*128 - 128);
  } else {
    pHi0 = xr0; pLo0 = (tA0 < 54) ? (shlo + ((size_t)b0s*54 + tA0)*128) : xr0;
    pHi1 = xr1; pLo1 = (tA1 < 54) ? (shlo + ((size_t)b1s*54 + tA1)*128) : xr1;
  }
  const bf16* Bb = Bp + (size_t)(d*3 + nb) * 4096;

  if (L0) {
    for (int i = tid; i < 1792; i += 256) TBl[i] = (bf16)table[i];
    if (tid < 128) {
      int m = mb*128 + tid; int b = m / len; int tw = m - b*len;
      int t = d ? (t0b - tw) : (t0f + tw);
      int g = b*107 + t;
      tokl[tid] = seq[g]; tokl[128 + tid] = str[g]; tokl[256 + tid] = lp[g];
    }
  }

  f32x4 acc[4][4];
  #pragma unroll
  for (int i = 0; i < 4; ++i)
    #pragma unroll
    for (int j = 0; j < 4; ++j) { f32x4 z = {0.f,0.f,0.f,0.f}; acc[i][j] = z; }

  for (int kt = 0; kt < KT; ++kt) {
    __syncthreads();
    if (L0) {
      int ch = kt >> 2; int kc = (kt & 3) * 32;
      bf16x8 v0 = *reinterpret_cast<const bf16x8*>(TBl + tokl[ch*128 + r0]*128 + kc + sw0);
      bf16x8 v1 = *reinterpret_cast<const bf16x8*>(TBl + tokl[ch*128 + r1]*128 + kc + sw1);
      *reinterpret_cast<bf16x8*>(As + c0*8) = v0;
      *reinterpret_cast<bf16x8*>(As + c1*8) = v1;
    } else {
      gload16((kt < 4 ? pLo0 : pHi0) + (size_t)kt*32 + sw0, As + (size_t)c0*8);
      gload16((kt < 4 ? pLo1 : pHi1) + (size_t)kt*32 + sw1, As + (size_t)c1*8);
    }
    gload16(Bb + (size_t)kt*6*4096 + c0*8, Bs + (size_t)c0*8);
    gload16(Bb + (size_t)kt*6*4096 + c1*8, Bs + (size_t)c1*8);
    __syncthreads();
    bf16x8 af[4], bfr[4];
    #pragma unroll
    for (int mt = 0; mt < 4; ++mt) {
      int r = wm*64 + mt*16 + l4;
      af[mt] = *reinterpret_cast<const bf16x8*>(As + r*32 + ((g4 ^ (r & 3)) * 8));
    }
    #pragma unroll
    for (int nt = 0; nt < 4; ++nt)
      bfr[nt] = *reinterpret_cast<const bf16x8*>(Bs + ((wn*4 + nt)*64 + lane)*8);
    #pragma unroll
    for (int mt = 0; mt < 4; ++mt)
      #pragma unroll
      for (int nt = 0; nt < 4; ++nt)
        acc[mt][nt] = __builtin_amdgcn_mfma_f32_16x16x32_bf16(af[mt], bfr[nt], acc[mt][nt], 0, 0, 0);
  }
  int n_local = nb*128 + wn*64;
  #pragma unroll
  for (int mt = 0; mt < 4; ++mt)
    #pragma unroll
    for (int nt = 0; nt < 4; ++nt) {
      int col = n_local + nt*16 + l4;
      float bv = bias[d*384 + col];
      #pragma unroll
      for (int i = 0; i < 4; ++i) {
        int m = mb*128 + wm*64 + mt*16 + g4*4 + i;
        int b = m / len; int tw = m - b*len;
        xpw[(((size_t)d*2048 + b)*len + tw)*384 + col] = (bf16)(acc[mt][nt][i] + bv);
      }
    }
}

// ---------------- GRU scan (one layer, one time window, full batch) ----------------
// grid (128, 2): 16 batch rows/block, 4 waves; wave w owns h-cols [32w,32w+32).
// h state carried across windows in hst (f32 [dir][b][128]).
__global__ __launch_bounds__(256, 1) void scan_k(const bf16* __restrict__ xpw,
                                                 const bf16* __restrict__ whh,
                                                 const float* __restrict__ bhhn,
                                                 bf16* __restrict__ xout,
                                                 float* __restrict__ hst,
                                                 int len, int t0f, int t0b, int first) {
  __shared__ __align__(16) bf16 h_lds[2][2048];  // A-fragment order: [ks(4)][lane(64)][e(8)]
  int tid = threadIdx.x; int lane = tid & 63; int w = tid >> 6;
  int l4 = lane & 15, g4 = lane >> 4;
  int d = blockIdx.y;
  int b0 = blockIdx.x * 16;
  const bf16* xpb = xpw + (size_t)d * 2048 * len * 384;
  int ntl[6];
  ntl[0] = 2*w;    ntl[1] = 2*w + 1;
  ntl[2] = 8+2*w;  ntl[3] = 9+2*w;
  ntl[4] = 16+2*w; ntl[5] = 17+2*w;

  // Whh B-fragments fully in registers (constant over time)
  bf16x8 bw[6][4];
  #pragma unroll
  for (int nt = 0; nt < 6; ++nt)
    #pragma unroll
    for (int ks = 0; ks < 4; ++ks)
      bw[nt][ks] = *reinterpret_cast<const bf16x8*>(whh + ((size_t)(d*4 + ks)*24 + ntl[nt])*512 + lane*8);

  float bn[2];
  bn[0] = bhhn[d*128 + w*32 + l4];
  bn[1] = bhhn[d*128 + w*32 + 16 + l4];
  float h_own[2][4];

  if (first) {
    #pragma unroll
    for (int tau = 0; tau < 2; ++tau)
      #pragma unroll
      for (int i = 0; i < 4; ++i) h_own[tau][i] = 0.f;
    reinterpret_cast<float4*>(&h_lds[0][0])[tid] = make_float4(0.f, 0.f, 0.f, 0.f);
  } else {
    #pragma unroll
    for (int tau = 0; tau < 2; ++tau)
      #pragma unroll
      for (int i = 0; i < 4; ++i) {
        int j = w*32 + tau*16 + l4;
        h_own[tau][i] = hst[((size_t)d*2048 + b0 + g4*4 + i)*128 + j];
        int s = j >> 5, c3 = (j >> 3) & 3, e = j & 7;
        int m = g4*4 + i;
        h_lds[0][(s*64 + m + 16*c3)*8 + e] = (bf16)h_own[tau][i];
      }
  }

  bf16 xa[6][4], xb[6][4];
  { // prologue: load xp for tw=0
    #pragma unroll
    for (int nt = 0; nt < 6; ++nt)
      #pragma unroll
      for (int i = 0; i < 4; ++i)
        xa[nt][i] = xpb[(size_t)(b0 + g4*4 + i)*len*384 + ntl[nt]*16 + l4];
  }
  __syncthreads();

  auto step = [&](bf16 (&xu)[6][4], bf16 (&xl)[6][4], int tw, int pb) {
    int tc = d ? (t0b - tw) : (t0f + tw);
    int twn = (tw + 1 < len) ? (tw + 1) : (len - 1);
    // A-fragments of h from LDS (fragment-linear, conflict-free)
    bf16x8 a[4];
    #pragma unroll
    for (int ks = 0; ks < 4; ++ks)
      a[ks] = *reinterpret_cast<const bf16x8*>(&h_lds[pb][(ks*64 + lane)*8]);
    // prefetch next step's xp (latency hidden under MFMA+gates)
    #pragma unroll
    for (int nt = 0; nt < 6; ++nt)
      #pragma unroll
      for (int i = 0; i < 4; ++i)
        xl[nt][i] = xpb[((size_t)(b0 + g4*4 + i)*len + twn)*384 + ntl[nt]*16 + l4];
    // gh = h @ Whh^T
    f32x4 acc[6];
    #pragma unroll
    for (int nt = 0; nt < 6; ++nt) { f32x4 z = {0.f,0.f,0.f,0.f}; acc[nt] = z; }
    #pragma unroll
    for (int ks = 0; ks < 4; ++ks)
      #pragma unroll
      for (int nt = 0; nt < 6; ++nt)
        acc[nt] = __builtin_amdgcn_mfma_f32_16x16x32_bf16(a[ks], bw[nt][ks], acc[nt], 0, 0, 0);
    // gates
    bf16 hb[2][4];
    #pragma unroll
    for (int tau = 0; tau < 2; ++tau)
      #pragma unroll
      for (int i = 0; i < 4; ++i) {
        float xr = (float)xu[tau][i];
        float xz = (float)xu[2 + tau][i];
        float xn = (float)xu[4 + tau][i];
        float r = sigm(xr + acc[tau][i]);          // bih+bhh folded into xp
        float z = sigm(xz + acc[2 + tau][i]);
        float n = tanhx(xn + r * (acc[4 + tau][i] + bn[tau]));  // bhh_n inside r*( )
        float hv = (1.f - z) * n + z * h_own[tau][i];
        h_own[tau][i] = hv;
        hb[tau][i] = (bf16)hv;
      }
    // write new h into the OTHER buffer (no read/write conflict -> single barrier)
    #pragma unroll
    for (int tau = 0; tau < 2; ++tau)
      #pragma unroll
      for (int i = 0; i < 4; ++i) {
        int j = w*32 + tau*16 + l4;
        int s = j >> 5, c3 = (j >> 3) & 3, e = j & 7;
        int m = g4*4 + i;
        h_lds[pb ^ 1][(s*64 + m + 16*c3)*8 + e] = hb[tau][i];
        xout[((size_t)(b0 + m)*107 + tc)*256 + d*128 + j] = hb[tau][i];
      }
    __syncthreads();   // new-h writes visible; next step reads pb^1
  };

  for (int tw = 0; tw < len; ++tw) {
    if (tw & 1) step(xb, xa, tw, 1);
    else        step(xa, xb, tw, 0);
  }
  // persist h state
  #pragma unroll
  for (int tau = 0; tau < 2; ++tau)
    #pragma unroll
    for (int i = 0; i < 4; ++i) {
      int j = w*32 + tau*16 + l4;
      hst[((size_t)d*2048 + b0 + g4*4 + i)*128 + j] = h_own[tau][i];
    }
}

// ---------------- final linear ----------------
__global__ void final_k(const bf16* __restrict__ hs, const float* __restrict__ lw,
                        const float* __restrict__ lb, float* __restrict__ out) {
  __shared__ float wsm[768];
  int tid = threadIdx.x;
  for (int i = tid; i < 768; i += 256) wsm[i] = lw[i];
  __syncthreads();
  int idx = blockIdx.x * 256 + tid;           // 0..139263  (b*68 + t)
  int b = idx / 68, t = idx % 68;
  const bf16* row = hs + (size_t)(b*107 + t) * 256;
  float a0 = lb[0], a1 = lb[1], a2 = lb[2];
  for (int j0 = 0; j0 < 256; j0 += 8) {
    bf16x8 v = *reinterpret_cast<const bf16x8*>(row + j0);
    #pragma unroll
    for (int e = 0; e < 8; ++e) {
      float f = (float)v[e];
      a0 += f * wsm[(j0 + e)*3 + 0];
      a1 += f * wsm[(j0 + e)*3 + 1];
      a2 += f * wsm[(j0 + e)*3 + 2];
    }
  }
  out[(size_t)idx*3 + 0] = a0;
  out[(size_t)idx*3 + 1] = a1;
  out[(size_t)idx*3 + 2] = a2;
}

// ---------------- launch ----------------
extern "C" void kernel_launch(void* const* d_in, const int* in_sizes, int n_in,
                              void* d_out, int out_size, void* d_ws, size_t ws_size,
                              hipStream_t stream) {
  const int*   seq   = (const int*)d_in[0];
  const int*   str   = (const int*)d_in[1];
  const int*   lp    = (const int*)d_in[2];
  const float* table = (const float*)d_in[3];
  const float* w_ih  = (const float*)d_in[4];
  const float* w_hh  = (const float*)d_in[5];
  const float* b_ih  = (const float*)d_in[6];
  const float* b_hh  = (const float*)d_in[7];
  const float* lw    = (const float*)d_in[8];
  const float* lb    = (const float*)d_in[9];
  float* out = (float*)d_out;
  char* ws = (char*)d_ws;

  // ---- layout ----
  const size_t xsz    = (size_t)M_ * 256 * 2;        // 112,197,632
  const size_t shlosz = (size_t)2048*54*128*2;       // 28,311,552
  const size_t shhisz = (size_t)2048*53*128*2;       // 27,787,264
  const size_t wihsz  = (size_t)9*12*6*8*64*8 * 2;   // 5,308,416
  const size_t whhsz  = (size_t)9*2*4*24*64*8 * 2;   // 1,769,472
  const size_t biassz = 9*768*4, bhhnsz = 9*256*4;
  const size_t hstsz  = (size_t)2*2048*128*4;        // 2,097,152
  const size_t fixed  = xsz + shlosz + shhisz + wihsz + whhsz + biassz + bhhnsz + hstsz;
  int W = 32;
  while (W > 8 && fixed + (size_t)2*2048*W*384*2 > ws_size) W -= 8;
  const size_t xpwsz = (size_t)2*2048*W*384*2;

  size_t off = 0;
  bf16* X    = (bf16*)(ws + off); off += xsz;
  bf16* XPW  = (bf16*)(ws + off); off += xpwsz;
  bf16* SHLO = (bf16*)(ws + off); off += shlosz;
  bf16* SHHI = (bf16*)(ws + off); off += shhisz;
  bf16* WIH  = (bf16*)(ws + off); off += wihsz;
  bf16* WHH  = (bf16*)(ws + off); off += whhsz;
  float* BIAS = (float*)(ws + off); off += biassz;
  float* BHHN = (float*)(ws + off); off += bhhnsz;
  float* HST  = (float*)(ws + off);

  hipLaunchKernelGGL(pack_wih_k,  dim3(2654208/256), dim3(256), 0, stream, w_ih, WIH);
  hipLaunchKernelGGL(pack_whh_k,  dim3(884736/256),  dim3(256), 0, stream, w_hh, WHH);
  hipLaunchKernelGGL(pack_bias_k, dim3(27),          dim3(256), 0, stream, b_ih, b_hh, BIAS, BHHN);

  const int phases = (107 + W - 1) / W;
  for (int gl = 0; gl < 9; ++gl) {
    int L0 = (gl == 0) ? 1 : 0;
    int KT = L0 ? 12 : 8;
    if (!L0)
      hipLaunchKernelGGL(shadow_k, dim3(13696), dim3(256), 0, stream, X, SHLO, SHHI);
    for (int p = 0; p < phases; ++p) {
      int len = (107 - p*W < W) ? (107 - p*W) : W;
      int t0f = p*W;
      int t0b = 106 - p*W;
      hipLaunchKernelGGL(gemm_proj_k, dim3(16*len, 3, 2), dim3(256), 0, stream,
                         X, SHLO, SHHI, seq, str, lp, table, L0, KT,
                         WIH + (size_t)gl*294912, BIAS + gl*768, XPW, len, t0f, t0b);
      hipLaunchKernelGGL(scan_k, dim3(128, 2), dim3(256), 0, stream,
                         XPW, WHH + (size_t)gl*98304, BHHN + gl*256, X, HST,
                         len, t0f, t0b, (p == 0) ? 1 : 0);
    }
  }
  hipLaunchKernelGGL(final_k, dim3(544), dim3(256), 0, stream, X, lw, lb, out);
}

// Round 5
// 3326.611 us; speedup vs baseline: 2.3413x; 1.1352x over previous
//
#include <hip/hip_runtime.h>
#include <hip/hip_bf16.h>

// Problem constants
#define B_ 2048
#define L_ 107
#define E_ 128
#define H_ 128
#define PRED_ 68
#define M_ (B_*L_)   // 219136 rows

typedef __bf16 bf16;
typedef __bf16 bf16x8 __attribute__((ext_vector_type(8)));
typedef __bf16 bf16x4 __attribute__((ext_vector_type(4)));
typedef float f32x4 __attribute__((ext_vector_type(4)));

__device__ __forceinline__ void gload16(const void* g, void* l) {
  __builtin_amdgcn_global_load_lds(
      (const __attribute__((address_space(1))) unsigned int*)g,
      (__attribute__((address_space(3))) unsigned int*)l, 16, 0, 0);
}

__device__ __forceinline__ float sigm(float x)  { return 1.f / (1.f + __expf(-x)); }
__device__ __forceinline__ float tanhx(float x) { return 1.f - 2.f / (1.f + __expf(2.f * x)); }

// ---------------- pack kernels ----------------
// wih pack: [gl(9)][kt(12)][nb6(6)][nt(8)][lane(64)][e(8)]  (B-fragment-linear, value = Wih[n][k])
__global__ void pack_wih_k(const float* __restrict__ w_ih, bf16* __restrict__ out) {
  int idx = blockIdx.x * 256 + threadIdx.x;
  if (idx >= 9*12*6*8*64*8) return;
  int e = idx & 7;
  int lane = (idx >> 3) & 63;
  int q = idx >> 9;
  int nt = q & 7; q >>= 3;
  int nb = q % 6; q /= 6;
  int kt = q % 12; int gl = q / 12;
  int ng = nb*128 + nt*16 + (lane & 15);     // 0..767 : [dir0 384 | dir1 384]
  int k  = kt*32 + (lane >> 4)*8 + e;        // 0..383
  int d  = (ng >= 384) ? 1 : 0;
  int np = ng - d*384;
  float v = w_ih[(((size_t)(gl*2 + d)*384 + np)*384 + k)];
  out[idx] = (bf16)v;
}

// whh pack: [gl(9)][d(2)][ks(4)][nt(24)][lane(64)][e(8)]  (value = Whh[n][k])
__global__ void pack_whh_k(const float* __restrict__ w_hh, bf16* __restrict__ out) {
  int idx = blockIdx.x * 256 + threadIdx.x;
  if (idx >= 9*2*4*24*64*8) return;
  int e = idx & 7;
  int lane = (idx >> 3) & 63;
  int q = idx >> 9;
  int nt = q % 24; q /= 24;
  int ks = q & 3;  q >>= 2;
  int d  = q & 1;  int gl = q >> 1;
  int n = nt*16 + (lane & 15);
  int k = ks*32 + (lane >> 4)*8 + e;
  out[idx] = (bf16)w_hh[((size_t)(gl*2 + d)*384 + n)*128 + k];
}

// bias pack: bias[gl][768] = bih + (n<256 ? bhh : 0); bhhn[gl][d][128] = bhh[256+j]
__global__ void pack_bias_k(const float* __restrict__ b_ih, const float* __restrict__ b_hh,
                            float* __restrict__ bias, float* __restrict__ bhhn) {
  int idx = blockIdx.x * 256 + threadIdx.x;
  if (idx < 9*768) {
    int gl = idx / 768; int n = idx % 768;
    int d = (n >= 384) ? 1 : 0; int np = n - d*384;
    float v = b_ih[(gl*2 + d)*384 + np];
    if (np < 256) v += b_hh[(gl*2 + d)*384 + np];
    bias[idx] = v;
  }
  if (idx < 9*256) {
    int gl = idx / 256; int r = idx % 256;
    int d = (r >= 128) ? 1 : 0; int j = r & 127;
    bhhn[idx] = b_hh[(gl*2 + d)*384 + 256 + j];
  }
}

// ---------------- shadow copy (per layer >=1, before phases) ----------------
// SHLO[b][t<54][128]   = X[b][t][0:128]    (fwd halves, read late by bwd GEMM)
// SHHI[b][t-54][128]   = X[b][t][128:256]  (bwd halves, read late by fwd GEMM), t in [54,107)
__global__ void shadow_k(const bf16* __restrict__ X, bf16* __restrict__ shlo,
                         bf16* __restrict__ shhi) {
  int idx = blockIdx.x * 256 + threadIdx.x;      // one 8-elem chunk each
  const int NLO = 2048*54*16;
  if (idx < NLO) {
    int k8 = idx & 15; int q = idx >> 4; int t = q % 54; int b = q / 54;
    *reinterpret_cast<bf16x8*>(shlo + ((size_t)b*54 + t)*128 + k8*8) =
      *reinterpret_cast<const bf16x8*>(X + ((size_t)b*107 + t)*256 + k8*8);
  } else {
    idx -= NLO;
    int k8 = idx & 15; int q = idx >> 4; int t = 54 + q % 53; int b = q / 53;
    if (b < 2048)
      *reinterpret_cast<bf16x8*>(shhi + ((size_t)b*53 + (t-54))*128 + k8*8) =
        *reinterpret_cast<const bf16x8*>(X + ((size_t)b*107 + t)*256 + 128 + k8*8);
  }
}

// ---------------- projection GEMM (tw-major, dbuf, fragment-linear output) ----------------
// grid (len*16, 3, 2): blockIdx.x = tw*16 + mtile; 128 batch rows per block, uniform t.
// Output xpw fragment-linear: [d][tile_m(=tw*128+b/16)][tile_n(24)][lane*4+i]
__global__ __launch_bounds__(256) void gemm_proj_k(
    const bf16* __restrict__ Xin, const bf16* __restrict__ shlo, const bf16* __restrict__ shhi,
    const int* __restrict__ seq, const int* __restrict__ str, const int* __restrict__ lp,
    const float* __restrict__ table, int L0, int KT,
    const bf16* __restrict__ Bp, const float* __restrict__ bias,
    bf16* __restrict__ xpw, int len, int t0f, int t0b) {
  __shared__ __align__(16) bf16 As[2][128*32];
  __shared__ __align__(16) bf16 Bs[2][512*8];
  __shared__ __align__(16) bf16 TBl[14*136];   // padded stride vs 128 -> spreads banks
  __shared__ int tokl[3*128];
  int tid = threadIdx.x; int lane = tid & 63; int w = tid >> 6;
  int l4 = lane & 15, g4 = lane >> 4;
  int wm = w >> 1, wn = w & 1;
  int tw = blockIdx.x >> 4, mtile = blockIdx.x & 15;
  int nb = blockIdx.y, d = blockIdx.z;
  int t = d ? (t0b - tw) : (t0f + tw);

  // staging thread -> (row, chunk)
  int c0 = tid, c1 = tid + 256;
  int r0 = c0 >> 2, cc0 = c0 & 3;
  int r1 = c1 >> 2, cc1 = c1 & 3;
  int sw0 = ((cc0 ^ ((r0 >> 1) & 3)) * 8), sw1 = ((cc1 ^ ((r1 >> 1) & 3)) * 8);
  int b0g = mtile*128 + r0, b1g = mtile*128 + r1;
  const bf16* xr0 = Xin + ((size_t)b0g*107 + t)*256;
  const bf16* xr1 = Xin + ((size_t)b1g*107 + t)*256;
  const bf16 *pLo0, *pHi0, *pLo1, *pHi1;
  if (d == 0) {
    pLo0 = xr0; pHi0 = (t < 54) ? xr0 : (shhi + ((size_t)b0g*53 + (t-54))*128 - 128);
    pLo1 = xr1; pHi1 = (t < 54) ? xr1 : (shhi + ((size_t)b1g*53 + (t-54))*128 - 128);
  } else {
    pHi0 = xr0; pLo0 = (t < 54) ? (shlo + ((size_t)b0g*54 + t)*128) : xr0;
    pHi1 = xr1; pLo1 = (t < 54) ? (shlo + ((size_t)b1g*54 + t)*128) : xr1;
  }
  const bf16* Bb = Bp + (size_t)(d*3 + nb) * 4096;

  if (L0) {
    for (int i = tid; i < 1792; i += 256) TBl[(i >> 7)*136 + (i & 127)] = (bf16)table[i];
    if (tid < 128) {
      int b = mtile*128 + tid;
      int g = b*107 + t;
      tokl[tid] = seq[g]; tokl[128 + tid] = str[g]; tokl[256 + tid] = lp[g];
    }
  }

  // bias per thread (4 output col-tiles)
  float bias_r[4];
  #pragma unroll
  for (int nt = 0; nt < 4; ++nt)
    bias_r[nt] = bias[d*384 + nb*128 + wn*64 + nt*16 + l4];

  f32x4 acc[4][4];
  #pragma unroll
  for (int i = 0; i < 4; ++i)
    #pragma unroll
    for (int j = 0; j < 4; ++j) { f32x4 z = {0.f,0.f,0.f,0.f}; acc[i][j] = z; }

  // prologue: stage kt=0 into buf 0
  if (!L0) {
    gload16(pLo0 + sw0, &As[0][c0*8]);
    gload16(pLo1 + sw1, &As[0][c1*8]);
  }
  gload16(Bb + c0*8, &Bs[0][c0*8]);
  gload16(Bb + c1*8, &Bs[0][c1*8]);
  __syncthreads();

  for (int kt = 0; kt < KT; ++kt) {
    int cur = kt & 1, nxt = cur ^ 1;
    if (kt + 1 < KT) {           // stage kt+1 (in flight during MFMA below)
      int k1 = kt + 1;
      if (!L0) {
        gload16((k1 < 4 ? pLo0 : pHi0) + (size_t)k1*32 + sw0, &As[nxt][c0*8]);
        gload16((k1 < 4 ? pLo1 : pHi1) + (size_t)k1*32 + sw1, &As[nxt][c1*8]);
      }
      gload16(Bb + (size_t)k1*6*4096 + c0*8, &Bs[nxt][c0*8]);
      gload16(Bb + (size_t)k1*6*4096 + c1*8, &Bs[nxt][c1*8]);
    }
    bf16x8 af[4], bfr[4];
    if (L0) {
      int ch = kt >> 2; int kc = (kt & 3) * 32;
      #pragma unroll
      for (int mt = 0; mt < 4; ++mt) {
        int r = wm*64 + mt*16 + l4;
        af[mt] = *reinterpret_cast<const bf16x8*>(TBl + tokl[ch*128 + r]*136 + kc + g4*8);
      }
    } else {
      #pragma unroll
      for (int mt = 0; mt < 4; ++mt) {
        int r = wm*64 + mt*16 + l4;
        af[mt] = *reinterpret_cast<const bf16x8*>(&As[cur][r*32 + ((g4 ^ ((r >> 1) & 3)) * 8)]);
      }
    }
    #pragma unroll
    for (int nt = 0; nt < 4; ++nt)
      bfr[nt] = *reinterpret_cast<const bf16x8*>(&Bs[cur][((wn*4 + nt)*64 + lane)*8]);
    #pragma unroll
    for (int mt = 0; mt < 4; ++mt)
      #pragma unroll
      for (int nt = 0; nt < 4; ++nt)
        acc[mt][nt] = __builtin_amdgcn_mfma_f32_16x16x32_bf16(af[mt], bfr[nt], acc[mt][nt], 0, 0, 0);
    __syncthreads();   // drains next-stage loads (implicit vmcnt0) + publishes LDS
  }

  // epilogue: fragment-linear bf16x4 stores
  int tile_m_base = tw*128 + mtile*8 + wm*4;
  int tile_n_base = nb*8 + wn*4;
  size_t dbase = d ? (size_t)len*128*24*256 : 0;
  #pragma unroll
  for (int mt = 0; mt < 4; ++mt)
    #pragma unroll
    for (int nt = 0; nt < 4; ++nt) {
      f32x4 a = acc[mt][nt]; float bv = bias_r[nt];
      bf16x4 o;
      o[0] = (bf16)(a[0] + bv); o[1] = (bf16)(a[1] + bv);
      o[2] = (bf16)(a[2] + bv); o[3] = (bf16)(a[3] + bv);
      *reinterpret_cast<bf16x4*>(xpw + dbase +
          (((size_t)(tile_m_base + mt)*24 + tile_n_base + nt) << 8) + lane*4) = o;
    }
}

// ---------------- GRU scan (one layer, one time window, full batch) ----------------
// grid (128, 2): 16 batch rows/block, 4 waves; wave w owns h-cols [32w,32w+32).
__global__ __launch_bounds__(256, 1) void scan_k(const bf16* __restrict__ xpw,
                                                 const bf16* __restrict__ whh,
                                                 const float* __restrict__ bhhn,
                                                 bf16* __restrict__ xout,
                                                 float* __restrict__ hst,
                                                 int len, int t0f, int t0b, int first) {
  __shared__ __align__(16) bf16 h_lds[2][2048];  // A-fragment order: [ks(4)][lane(64)][e(8)]
  int tid = threadIdx.x; int lane = tid & 63; int w = tid >> 6;
  int l4 = lane & 15, g4 = lane >> 4;
  int d = blockIdx.y;
  int bx = blockIdx.x;
  int b0 = bx * 16;
  const bf16* xpb = xpw + (d ? (size_t)len*128*24*256 : 0);
  int ntl[6];
  ntl[0] = 2*w;    ntl[1] = 2*w + 1;
  ntl[2] = 8+2*w;  ntl[3] = 9+2*w;
  ntl[4] = 16+2*w; ntl[5] = 17+2*w;
  int fragoff = g4*64 + l4*4;

  // Whh B-fragments fully in registers (constant over time)
  bf16x8 bw[6][4];
  #pragma unroll
  for (int nt = 0; nt < 6; ++nt)
    #pragma unroll
    for (int ks = 0; ks < 4; ++ks)
      bw[nt][ks] = *reinterpret_cast<const bf16x8*>(whh + ((size_t)(d*4 + ks)*24 + ntl[nt])*512 + lane*8);

  float bn[2];
  bn[0] = bhhn[d*128 + w*32 + l4];
  bn[1] = bhhn[d*128 + w*32 + 16 + l4];
  float h_own[2][4];

  if (first) {
    #pragma unroll
    for (int tau = 0; tau < 2; ++tau)
      #pragma unroll
      for (int i = 0; i < 4; ++i) h_own[tau][i] = 0.f;
    reinterpret_cast<float4*>(&h_lds[0][0])[tid] = make_float4(0.f, 0.f, 0.f, 0.f);
  } else {
    #pragma unroll
    for (int tau = 0; tau < 2; ++tau)
      #pragma unroll
      for (int i = 0; i < 4; ++i) {
        int j = w*32 + tau*16 + l4;
        h_own[tau][i] = hst[((size_t)d*2048 + b0 + g4*4 + i)*128 + j];
        int s = j >> 5, c3 = (j >> 3) & 3, e = j & 7;
        int m = g4*4 + i;
        h_lds[0][(s*64 + m + 16*c3)*8 + e] = (bf16)h_own[tau][i];
      }
  }

  bf16x4 xa[6], xb[6];
  { // prologue: load xp for tw=0 (tile_m = bx)
    #pragma unroll
    for (int nt = 0; nt < 6; ++nt)
      xa[nt] = *reinterpret_cast<const bf16x4*>(xpb + (((size_t)bx*24 + ntl[nt]) << 8) + fragoff);
  }
  __syncthreads();

  auto step = [&](bf16x4 (&xu)[6], bf16x4 (&xl)[6], int tw, int pb) {
    int tc = d ? (t0b - tw) : (t0f + tw);
    int twn = (tw + 1 < len) ? (tw + 1) : (len - 1);
    // A-fragments of h from LDS (fragment-linear, conflict-free)
    bf16x8 a[4];
    #pragma unroll
    for (int ks = 0; ks < 4; ++ks)
      a[ks] = *reinterpret_cast<const bf16x8*>(&h_lds[pb][(ks*64 + lane)*8]);
    // prefetch next step's xp (vector; latency hidden under MFMA+gates)
    size_t tmn = (size_t)(twn*128 + bx)*24;
    #pragma unroll
    for (int nt = 0; nt < 6; ++nt)
      xl[nt] = *reinterpret_cast<const bf16x4*>(xpb + ((tmn + ntl[nt]) << 8) + fragoff);
    // gh = h @ Whh^T
    f32x4 acc[6];
    #pragma unroll
    for (int nt = 0; nt < 6; ++nt) { f32x4 z = {0.f,0.f,0.f,0.f}; acc[nt] = z; }
    #pragma unroll
    for (int ks = 0; ks < 4; ++ks)
      #pragma unroll
      for (int nt = 0; nt < 6; ++nt)
        acc[nt] = __builtin_amdgcn_mfma_f32_16x16x32_bf16(a[ks], bw[nt][ks], acc[nt], 0, 0, 0);
    // gates
    #pragma unroll
    for (int tau = 0; tau < 2; ++tau)
      #pragma unroll
      for (int i = 0; i < 4; ++i) {
        float xr = (float)xu[tau][i];
        float xz = (float)xu[2 + tau][i];
        float xn = (float)xu[4 + tau][i];
        float r = sigm(xr + acc[tau][i]);          // bih+bhh folded into xp
        float z = sigm(xz + acc[2 + tau][i]);
        float n = tanhx(xn + r * (acc[4 + tau][i] + bn[tau]));  // bhh_n inside r*( )
        float hv = (1.f - z) * n + z * h_own[tau][i];
        h_own[tau][i] = hv;
        int j = w*32 + tau*16 + l4;
        int s = j >> 5, c3 = (j >> 3) & 3, e = j & 7;
        int m = g4*4 + i;
        h_lds[pb ^ 1][(s*64 + m + 16*c3)*8 + e] = (bf16)hv;
      }
    __syncthreads();   // new-h visible to all
    // repacked X write: 16B per thread from h_lds[pb^1]
    {
      int mo = tid & 15, sc = tid >> 4;
      int s = sc >> 2, c3 = sc & 3;
      bf16x8 v = *reinterpret_cast<const bf16x8*>(&h_lds[pb ^ 1][s*512 + c3*128 + mo*8]);
      *reinterpret_cast<bf16x8*>(xout + ((size_t)(b0 + mo)*107 + tc)*256 + d*128 + s*32 + c3*8) = v;
    }
  };

  for (int tw = 0; tw < len; ++tw) {
    if (tw & 1) step(xb, xa, tw, 1);
    else        step(xa, xb, tw, 0);
  }
  // persist h state
  #pragma unroll
  for (int tau = 0; tau < 2; ++tau)
    #pragma unroll
    for (int i = 0; i < 4; ++i) {
      int j = w*32 + tau*16 + l4;
      hst[((size_t)d*2048 + b0 + g4*4 + i)*128 + j] = h_own[tau][i];
    }
}

// ---------------- final linear ----------------
__global__ void final_k(const bf16* __restrict__ hs, const float* __restrict__ lw,
                        const float* __restrict__ lb, float* __restrict__ out) {
  __shared__ float wsm[768];
  int tid = threadIdx.x;
  for (int i = tid; i < 768; i += 256) wsm[i] = lw[i];
  __syncthreads();
  int idx = blockIdx.x * 256 + tid;           // 0..139263  (b*68 + t)
  int b = idx / 68, t = idx % 68;
  const bf16* row = hs + (size_t)(b*107 + t) * 256;
  float a0 = lb[0], a1 = lb[1], a2 = lb[2];
  for (int j0 = 0; j0 < 256; j0 += 8) {
    bf16x8 v = *reinterpret_cast<const bf16x8*>(row + j0);
    #pragma unroll
    for (int e = 0; e < 8; ++e) {
      float f = (float)v[e];
      a0 += f * wsm[(j0 + e)*3 + 0];
      a1 += f * wsm[(j0 + e)*3 + 1];
      a2 += f * wsm[(j0 + e)*3 + 2];
    }
  }
  out[(size_t)idx*3 + 0] = a0;
  out[(size_t)idx*3 + 1] = a1;
  out[(size_t)idx*3 + 2] = a2;
}

// ---------------- launch ----------------
extern "C" void kernel_launch(void* const* d_in, const int* in_sizes, int n_in,
                              void* d_out, int out_size, void* d_ws, size_t ws_size,
                              hipStream_t stream) {
  const int*   seq   = (const int*)d_in[0];
  const int*   str   = (const int*)d_in[1];
  const int*   lp    = (const int*)d_in[2];
  const float* table = (const float*)d_in[3];
  const float* w_ih  = (const float*)d_in[4];
  const float* w_hh  = (const float*)d_in[5];
  const float* b_ih  = (const float*)d_in[6];
  const float* b_hh  = (const float*)d_in[7];
  const float* lw    = (const float*)d_in[8];
  const float* lb    = (const float*)d_in[9];
  float* out = (float*)d_out;
  char* ws = (char*)d_ws;

  // ---- layout ----
  const size_t xsz    = (size_t)M_ * 256 * 2;        // 112,197,632
  const size_t shlosz = (size_t)2048*54*128*2;       // 28,311,552
  const size_t shhisz = (size_t)2048*53*128*2;       // 27,787,264
  const size_t wihsz  = (size_t)9*12*6*8*64*8 * 2;   // 5,308,416
  const size_t whhsz  = (size_t)9*2*4*24*64*8 * 2;   // 1,769,472
  const size_t biassz = 9*768*4, bhhnsz = 9*256*4;
  const size_t hstsz  = (size_t)2*2048*128*4;        // 2,097,152
  const size_t fixed  = xsz + shlosz + shhisz + wihsz + whhsz + biassz + bhhnsz + hstsz;
  int W = 32;
  while (W > 8 && fixed + (size_t)2*2048*W*384*2 > ws_size) W -= 8;
  const size_t xpwsz = (size_t)2*2048*W*384*2;

  size_t off = 0;
  bf16* X    = (bf16*)(ws + off); off += xsz;
  bf16* XPW  = (bf16*)(ws + off); off += xpwsz;
  bf16* SHLO = (bf16*)(ws + off); off += shlosz;
  bf16* SHHI = (bf16*)(ws + off); off += shhisz;
  bf16* WIH  = (bf16*)(ws + off); off += wihsz;
  bf16* WHH  = (bf16*)(ws + off); off += whhsz;
  float* BIAS = (float*)(ws + off); off += biassz;
  float* BHHN = (float*)(ws + off); off += bhhnsz;
  float* HST  = (float*)(ws + off);

  hipLaunchKernelGGL(pack_wih_k,  dim3(2654208/256), dim3(256), 0, stream, w_ih, WIH);
  hipLaunchKernelGGL(pack_whh_k,  dim3(884736/256),  dim3(256), 0, stream, w_hh, WHH);
  hipLaunchKernelGGL(pack_bias_k, dim3(27),          dim3(256), 0, stream, b_ih, b_hh, BIAS, BHHN);

  const int phases = (107 + W - 1) / W;
  for (int gl = 0; gl < 9; ++gl) {
    int L0 = (gl == 0) ? 1 : 0;
    int KT = L0 ? 12 : 8;
    if (!L0)
      hipLaunchKernelGGL(shadow_k, dim3(13696), dim3(256), 0, stream, X, SHLO, SHHI);
    for (int p = 0; p < phases; ++p) {
      int len = (107 - p*W < W) ? (107 - p*W) : W;
      int t0f = p*W;
      int t0b = 106 - p*W;
      hipLaunchKernelGGL(gemm_proj_k, dim3(len*16, 3, 2), dim3(256), 0, stream,
                         X, SHLO, SHHI, seq, str, lp, table, L0, KT,
                         WIH + (size_t)gl*294912, BIAS + gl*768, XPW, len, t0f, t0b);
      hipLaunchKernelGGL(scan_k, dim3(128, 2), dim3(256), 0, stream,
                         XPW, WHH + (size_t)gl*98304, BHHN + gl*256, X, HST,
                         len, t0f, t0b, (p == 0) ? 1 : 0);
    }
  }
  hipLaunchKernelGGL(final_k, dim3(544), dim3(256), 0, stream, X, lw, lb, out);
}

// Round 6
// 3146.159 us; speedup vs baseline: 2.4756x; 1.0574x over previous
//
#include <hip/hip_runtime.h>
#include <hip/hip_bf16.h>

// Problem constants
#define B_ 2048
#define L_ 107
#define E_ 128
#define H_ 128
#define PRED_ 68
#define M_ (B_*L_)   // 219136 rows

typedef __bf16 bf16;
typedef __bf16 bf16x8 __attribute__((ext_vector_type(8)));
typedef __bf16 bf16x4 __attribute__((ext_vector_type(4)));
typedef float f32x4 __attribute__((ext_vector_type(4)));

__device__ __forceinline__ void gload16(const void* g, void* l) {
  __builtin_amdgcn_global_load_lds(
      (const __attribute__((address_space(1))) unsigned int*)g,
      (__attribute__((address_space(3))) unsigned int*)l, 16, 0, 0);
}

__device__ __forceinline__ float sigm(float x)  { return 1.f / (1.f + __expf(-x)); }
__device__ __forceinline__ float tanhx(float x) { return 1.f - 2.f / (1.f + __expf(2.f * x)); }

// ---------------- pack kernels ----------------
// wih pack: [gl(9)][kt(12)][nb6(6)][nt(8)][lane(64)][e(8)]  (B-fragment-linear, value = Wih[n][k])
__global__ void pack_wih_k(const float* __restrict__ w_ih, bf16* __restrict__ out) {
  int idx = blockIdx.x * 256 + threadIdx.x;
  if (idx >= 9*12*6*8*64*8) return;
  int e = idx & 7;
  int lane = (idx >> 3) & 63;
  int q = idx >> 9;
  int nt = q & 7; q >>= 3;
  int nb = q % 6; q /= 6;
  int kt = q % 12; int gl = q / 12;
  int ng = nb*128 + nt*16 + (lane & 15);     // 0..767 : [dir0 384 | dir1 384]
  int k  = kt*32 + (lane >> 4)*8 + e;        // 0..383
  int d  = (ng >= 384) ? 1 : 0;
  int np = ng - d*384;
  float v = w_ih[(((size_t)(gl*2 + d)*384 + np)*384 + k)];
  out[idx] = (bf16)v;
}

// whh pack: [gl(9)][d(2)][ks(4)][nt(24)][lane(64)][e(8)]  (value = Whh[n][k])
__global__ void pack_whh_k(const float* __restrict__ w_hh, bf16* __restrict__ out) {
  int idx = blockIdx.x * 256 + threadIdx.x;
  if (idx >= 9*2*4*24*64*8) return;
  int e = idx & 7;
  int lane = (idx >> 3) & 63;
  int q = idx >> 9;
  int nt = q % 24; q /= 24;
  int ks = q & 3;  q >>= 2;
  int d  = q & 1;  int gl = q >> 1;
  int n = nt*16 + (lane & 15);
  int k = ks*32 + (lane >> 4)*8 + e;
  out[idx] = (bf16)w_hh[((size_t)(gl*2 + d)*384 + n)*128 + k];
}

// bias pack: bias[gl][768] = bih + (n<256 ? bhh : 0); bhhn[gl][d][128] = bhh[256+j]
__global__ void pack_bias_k(const float* __restrict__ b_ih, const float* __restrict__ b_hh,
                            float* __restrict__ bias, float* __restrict__ bhhn) {
  int idx = blockIdx.x * 256 + threadIdx.x;
  if (idx < 9*768) {
    int gl = idx / 768; int n = idx % 768;
    int d = (n >= 384) ? 1 : 0; int np = n - d*384;
    float v = b_ih[(gl*2 + d)*384 + np];
    if (np < 256) v += b_hh[(gl*2 + d)*384 + np];
    bias[idx] = v;
  }
  if (idx < 9*256) {
    int gl = idx / 256; int r = idx % 256;
    int d = (r >= 128) ? 1 : 0; int j = r & 127;
    bhhn[idx] = b_hh[(gl*2 + d)*384 + 256 + j];
  }
}

// ---------------- shadow copy (per layer >=1, before phases) ----------------
__global__ void shadow_k(const bf16* __restrict__ X, bf16* __restrict__ shlo,
                         bf16* __restrict__ shhi) {
  int idx = blockIdx.x * 256 + threadIdx.x;      // one 8-elem chunk each
  const int NLO = 2048*54*16;
  if (idx < NLO) {
    int k8 = idx & 15; int q = idx >> 4; int t = q % 54; int b = q / 54;
    *reinterpret_cast<bf16x8*>(shlo + ((size_t)b*54 + t)*128 + k8*8) =
      *reinterpret_cast<const bf16x8*>(X + ((size_t)b*107 + t)*256 + k8*8);
  } else {
    idx -= NLO;
    int k8 = idx & 15; int q = idx >> 4; int t = 54 + q % 53; int b = q / 53;
    if (b < 2048)
      *reinterpret_cast<bf16x8*>(shhi + ((size_t)b*53 + (t-54))*128 + k8*8) =
        *reinterpret_cast<const bf16x8*>(X + ((size_t)b*107 + t)*256 + 128 + k8*8);
  }
}

// ---------------- projection GEMM (tw-major, dbuf, fragment-linear output) ----------------
__global__ __launch_bounds__(256) void gemm_proj_k(
    const bf16* __restrict__ Xin, const bf16* __restrict__ shlo, const bf16* __restrict__ shhi,
    const int* __restrict__ seq, const int* __restrict__ str, const int* __restrict__ lp,
    const float* __restrict__ table, int L0, int KT,
    const bf16* __restrict__ Bp, const float* __restrict__ bias,
    bf16* __restrict__ xpw, int len, int t0f, int t0b) {
  __shared__ __align__(16) bf16 As[2][128*32];
  __shared__ __align__(16) bf16 Bs[2][512*8];
  __shared__ __align__(16) bf16 TBl[14*136];   // padded stride vs 128 -> spreads banks
  __shared__ int tokl[3*128];
  int tid = threadIdx.x; int lane = tid & 63; int w = tid >> 6;
  int l4 = lane & 15, g4 = lane >> 4;
  int wm = w >> 1, wn = w & 1;
  int tw = blockIdx.x >> 4, mtile = blockIdx.x & 15;
  int nb = blockIdx.y, d = blockIdx.z;
  int t = d ? (t0b - tw) : (t0f + tw);

  int c0 = tid, c1 = tid + 256;
  int r0 = c0 >> 2, cc0 = c0 & 3;
  int r1 = c1 >> 2, cc1 = c1 & 3;
  int sw0 = ((cc0 ^ ((r0 >> 1) & 3)) * 8), sw1 = ((cc1 ^ ((r1 >> 1) & 3)) * 8);
  int b0g = mtile*128 + r0, b1g = mtile*128 + r1;
  const bf16* xr0 = Xin + ((size_t)b0g*107 + t)*256;
  const bf16* xr1 = Xin + ((size_t)b1g*107 + t)*256;
  const bf16 *pLo0, *pHi0, *pLo1, *pHi1;
  if (d == 0) {
    pLo0 = xr0; pHi0 = (t < 54) ? xr0 : (shhi + ((size_t)b0g*53 + (t-54))*128 - 128);
    pLo1 = xr1; pHi1 = (t < 54) ? xr1 : (shhi + ((size_t)b1g*53 + (t-54))*128 - 128);
  } else {
    pHi0 = xr0; pLo0 = (t < 54) ? (shlo + ((size_t)b0g*54 + t)*128) : xr0;
    pHi1 = xr1; pLo1 = (t < 54) ? (shlo + ((size_t)b1g*54 + t)*128) : xr1;
  }
  const bf16* Bb = Bp + (size_t)(d*3 + nb) * 4096;

  if (L0) {
    for (int i = tid; i < 1792; i += 256) TBl[(i >> 7)*136 + (i & 127)] = (bf16)table[i];
    if (tid < 128) {
      int b = mtile*128 + tid;
      int g = b*107 + t;
      tokl[tid] = seq[g]; tokl[128 + tid] = str[g]; tokl[256 + tid] = lp[g];
    }
  }

  float bias_r[4];
  #pragma unroll
  for (int nt = 0; nt < 4; ++nt)
    bias_r[nt] = bias[d*384 + nb*128 + wn*64 + nt*16 + l4];

  f32x4 acc[4][4];
  #pragma unroll
  for (int i = 0; i < 4; ++i)
    #pragma unroll
    for (int j = 0; j < 4; ++j) { f32x4 z = {0.f,0.f,0.f,0.f}; acc[i][j] = z; }

  if (!L0) {
    gload16(pLo0 + sw0, &As[0][c0*8]);
    gload16(pLo1 + sw1, &As[0][c1*8]);
  }
  gload16(Bb + c0*8, &Bs[0][c0*8]);
  gload16(Bb + c1*8, &Bs[0][c1*8]);
  __syncthreads();

  for (int kt = 0; kt < KT; ++kt) {
    int cur = kt & 1, nxt = cur ^ 1;
    if (kt + 1 < KT) {           // stage kt+1 (in flight during MFMA below)
      int k1 = kt + 1;
      if (!L0) {
        gload16((k1 < 4 ? pLo0 : pHi0) + (size_t)k1*32 + sw0, &As[nxt][c0*8]);
        gload16((k1 < 4 ? pLo1 : pHi1) + (size_t)k1*32 + sw1, &As[nxt][c1*8]);
      }
      gload16(Bb + (size_t)k1*6*4096 + c0*8, &Bs[nxt][c0*8]);
      gload16(Bb + (size_t)k1*6*4096 + c1*8, &Bs[nxt][c1*8]);
    }
    bf16x8 af[4], bfr[4];
    if (L0) {
      int ch = kt >> 2; int kc = (kt & 3) * 32;
      #pragma unroll
      for (int mt = 0; mt < 4; ++mt) {
        int r = wm*64 + mt*16 + l4;
        af[mt] = *reinterpret_cast<const bf16x8*>(TBl + tokl[ch*128 + r]*136 + kc + g4*8);
      }
    } else {
      #pragma unroll
      for (int mt = 0; mt < 4; ++mt) {
        int r = wm*64 + mt*16 + l4;
        af[mt] = *reinterpret_cast<const bf16x8*>(&As[cur][r*32 + ((g4 ^ ((r >> 1) & 3)) * 8)]);
      }
    }
    #pragma unroll
    for (int nt = 0; nt < 4; ++nt)
      bfr[nt] = *reinterpret_cast<const bf16x8*>(&Bs[cur][((wn*4 + nt)*64 + lane)*8]);
    #pragma unroll
    for (int mt = 0; mt < 4; ++mt)
      #pragma unroll
      for (int nt = 0; nt < 4; ++nt)
        acc[mt][nt] = __builtin_amdgcn_mfma_f32_16x16x32_bf16(af[mt], bfr[nt], acc[mt][nt], 0, 0, 0);
    __syncthreads();   // drains next-stage loads (implicit vmcnt0) + publishes LDS
  }

  // epilogue: fragment-linear bf16x4 stores
  int tile_m_base = tw*128 + mtile*8 + wm*4;
  int tile_n_base = nb*8 + wn*4;
  size_t dbase = d ? (size_t)len*128*24*256 : 0;
  #pragma unroll
  for (int mt = 0; mt < 4; ++mt)
    #pragma unroll
    for (int nt = 0; nt < 4; ++nt) {
      f32x4 a = acc[mt][nt]; float bv = bias_r[nt];
      bf16x4 o;
      o[0] = (bf16)(a[0] + bv); o[1] = (bf16)(a[1] + bv);
      o[2] = (bf16)(a[2] + bv); o[3] = (bf16)(a[3] + bv);
      *reinterpret_cast<bf16x4*>(xpw + dbase +
          (((size_t)(tile_m_base + mt)*24 + tile_n_base + nt) << 8) + lane*4) = o;
    }
}

// ---------------- GRU scan (one layer, one time window, full batch) ----------------
// grid (128, 2), 512 threads (8 waves, 2/SIMD): 16 batch rows/block;
// wave w owns h-cols [16w,16w+16) -> MFMA n-tiles {w, 8+w, 16+w} (r,z,n).
__global__ __launch_bounds__(512, 1) void scan_k(const bf16* __restrict__ xpw,
                                                 const bf16* __restrict__ whh,
                                                 const float* __restrict__ bhhn,
                                                 bf16* __restrict__ xout,
                                                 float* __restrict__ hst,
                                                 int len, int t0f, int t0b, int first) {
  __shared__ __align__(16) bf16 h_lds[2][2048];  // A-fragment order: [ks(4)][lane(64)][e(8)]
  int tid = threadIdx.x; int lane = tid & 63; int w = tid >> 6;   // 0..7
  int l4 = lane & 15, g4 = lane >> 4;
  int d = blockIdx.y;
  int bx = blockIdx.x;
  int b0 = bx * 16;
  const bf16* xpb = xpw + (d ? (size_t)len*128*24*256 : 0);
  int ntl[3] = { w, 8 + w, 16 + w };
  int fragoff = g4*64 + l4*4;
  int j = w*16 + l4;                 // owned h-col
  int js = j >> 5, jc3 = (j >> 3) & 3, je = j & 7;

  // Whh B-fragments in registers (constant over time): 3 n-tiles x 4 k-slices
  bf16x8 bw[3][4];
  #pragma unroll
  for (int nt = 0; nt < 3; ++nt)
    #pragma unroll
    for (int ks = 0; ks < 4; ++ks)
      bw[nt][ks] = *reinterpret_cast<const bf16x8*>(whh + ((size_t)(d*4 + ks)*24 + ntl[nt])*512 + lane*8);

  float bn = bhhn[d*128 + j];
  float h_own[4];

  if (first) {
    #pragma unroll
    for (int i = 0; i < 4; ++i) h_own[i] = 0.f;
    if (tid < 256) reinterpret_cast<float4*>(&h_lds[0][0])[tid] = make_float4(0.f, 0.f, 0.f, 0.f);
  } else {
    #pragma unroll
    for (int i = 0; i < 4; ++i) {
      h_own[i] = hst[((size_t)d*2048 + b0 + g4*4 + i)*128 + j];
      int m = g4*4 + i;
      h_lds[0][(js*64 + m + 16*jc3)*8 + je] = (bf16)h_own[i];
    }
  }

  bf16x4 xa[3], xb[3];
  { // prologue: load xp for tw=0 (tile_m = bx)
    #pragma unroll
    for (int nt = 0; nt < 3; ++nt)
      xa[nt] = *reinterpret_cast<const bf16x4*>(xpb + (((size_t)bx*24 + ntl[nt]) << 8) + fragoff);
  }
  __syncthreads();

  auto step = [&](bf16x4 (&xu)[3], bf16x4 (&xl)[3], int tw, int pb) {
    int tc = d ? (t0b - tw) : (t0f + tw);
    int twn = (tw + 1 < len) ? (tw + 1) : (len - 1);
    // A-fragments of h from LDS (fragment-linear, conflict-free)
    bf16x8 a[4];
    #pragma unroll
    for (int ks = 0; ks < 4; ++ks)
      a[ks] = *reinterpret_cast<const bf16x8*>(&h_lds[pb][(ks*64 + lane)*8]);
    // prefetch next step's xp (vector; latency hidden under MFMA+gates)
    size_t tmn = (size_t)(twn*128 + bx)*24;
    #pragma unroll
    for (int nt = 0; nt < 3; ++nt)
      xl[nt] = *reinterpret_cast<const bf16x4*>(xpb + ((tmn + ntl[nt]) << 8) + fragoff);
    // gh = h @ Whh^T  (3 n-tiles: r,z,n for this wave's col group)
    f32x4 acc[3];
    #pragma unroll
    for (int nt = 0; nt < 3; ++nt) { f32x4 z = {0.f,0.f,0.f,0.f}; acc[nt] = z; }
    #pragma unroll
    for (int ks = 0; ks < 4; ++ks)
      #pragma unroll
      for (int nt = 0; nt < 3; ++nt)
        acc[nt] = __builtin_amdgcn_mfma_f32_16x16x32_bf16(a[ks], bw[nt][ks], acc[nt], 0, 0, 0);
    // gates (4 rows x 1 col per thread)
    #pragma unroll
    for (int i = 0; i < 4; ++i) {
      float r = sigm((float)xu[0][i] + acc[0][i]);          // bih+bhh folded into xp
      float z = sigm((float)xu[1][i] + acc[1][i]);
      float n = tanhx((float)xu[2][i] + r * (acc[2][i] + bn));  // bhh_n inside r*( )
      float hv = (1.f - z) * n + z * h_own[i];
      h_own[i] = hv;
      int m = g4*4 + i;
      h_lds[pb ^ 1][(js*64 + m + 16*jc3)*8 + je] = (bf16)hv;
    }
    __syncthreads();   // new-h visible to all
    // repacked X write: 16B per thread (first 4 waves) from h_lds[pb^1]
    if (tid < 256) {
      int mo = tid & 15, sc = tid >> 4;
      int s = sc >> 2, c3 = sc & 3;
      bf16x8 v = *reinterpret_cast<const bf16x8*>(&h_lds[pb ^ 1][s*512 + c3*128 + mo*8]);
      *reinterpret_cast<bf16x8*>(xout + ((size_t)(b0 + mo)*107 + tc)*256 + d*128 + s*32 + c3*8) = v;
    }
  };

  for (int tw = 0; tw < len; ++tw) {
    if (tw & 1) step(xb, xa, tw, 1);
    else        step(xa, xb, tw, 0);
  }
  // persist h state
  #pragma unroll
  for (int i = 0; i < 4; ++i)
    hst[((size_t)d*2048 + b0 + g4*4 + i)*128 + j] = h_own[i];
}

// ---------------- final linear ----------------
__global__ void final_k(const bf16* __restrict__ hs, const float* __restrict__ lw,
                        const float* __restrict__ lb, float* __restrict__ out) {
  __shared__ float wsm[768];
  int tid = threadIdx.x;
  for (int i = tid; i < 768; i += 256) wsm[i] = lw[i];
  __syncthreads();
  int idx = blockIdx.x * 256 + tid;           // 0..139263  (b*68 + t)
  int b = idx / 68, t = idx % 68;
  const bf16* row = hs + (size_t)(b*107 + t) * 256;
  float a0 = lb[0], a1 = lb[1], a2 = lb[2];
  for (int j0 = 0; j0 < 256; j0 += 8) {
    bf16x8 v = *reinterpret_cast<const bf16x8*>(row + j0);
    #pragma unroll
    for (int e = 0; e < 8; ++e) {
      float f = (float)v[e];
      a0 += f * wsm[(j0 + e)*3 + 0];
      a1 += f * wsm[(j0 + e)*3 + 1];
      a2 += f * wsm[(j0 + e)*3 + 2];
    }
  }
  out[(size_t)idx*3 + 0] = a0;
  out[(size_t)idx*3 + 1] = a1;
  out[(size_t)idx*3 + 2] = a2;
}

// ---------------- launch ----------------
extern "C" void kernel_launch(void* const* d_in, const int* in_sizes, int n_in,
                              void* d_out, int out_size, void* d_ws, size_t ws_size,
                              hipStream_t stream) {
  const int*   seq   = (const int*)d_in[0];
  const int*   str   = (const int*)d_in[1];
  const int*   lp    = (const int*)d_in[2];
  const float* table = (const float*)d_in[3];
  const float* w_ih  = (const float*)d_in[4];
  const float* w_hh  = (const float*)d_in[5];
  const float* b_ih  = (const float*)d_in[6];
  const float* b_hh  = (const float*)d_in[7];
  const float* lw    = (const float*)d_in[8];
  const float* lb    = (const float*)d_in[9];
  float* out = (float*)d_out;
  char* ws = (char*)d_ws;

  // ---- layout ----
  const size_t xsz    = (size_t)M_ * 256 * 2;        // 112,197,632
  const size_t shlosz = (size_t)2048*54*128*2;       // 28,311,552
  const size_t shhisz = (size_t)2048*53*128*2;       // 27,787,264
  const size_t wihsz  = (size_t)9*12*6*8*64*8 * 2;   // 5,308,416
  const size_t whhsz  = (size_t)9*2*4*24*64*8 * 2;   // 1,769,472
  const size_t biassz = 9*768*4, bhhnsz = 9*256*4;
  const size_t hstsz  = (size_t)2*2048*128*4;        // 2,097,152
  const size_t fixed  = xsz + shlosz + shhisz + wihsz + whhsz + biassz + bhhnsz + hstsz;
  int W = 32;
  while (W > 8 && fixed + (size_t)2*2048*W*384*2 > ws_size) W -= 8;
  const size_t xpwsz = (size_t)2*2048*W*384*2;

  size_t off = 0;
  bf16* X    = (bf16*)(ws + off); off += xsz;
  bf16* XPW  = (bf16*)(ws + off); off += xpwsz;
  bf16* SHLO = (bf16*)(ws + off); off += shlosz;
  bf16* SHHI = (bf16*)(ws + off); off += shhisz;
  bf16* WIH  = (bf16*)(ws + off); off += wihsz;
  bf16* WHH  = (bf16*)(ws + off); off += whhsz;
  float* BIAS = (float*)(ws + off); off += biassz;
  float* BHHN = (float*)(ws + off); off += bhhnsz;
  float* HST  = (float*)(ws + off);

  hipLaunchKernelGGL(pack_wih_k,  dim3(2654208/256), dim3(256), 0, stream, w_ih, WIH);
  hipLaunchKernelGGL(pack_whh_k,  dim3(884736/256),  dim3(256), 0, stream, w_hh, WHH);
  hipLaunchKernelGGL(pack_bias_k, dim3(27),          dim3(256), 0, stream, b_ih, b_hh, BIAS, BHHN);

  const int phases = (107 + W - 1) / W;
  for (int gl = 0; gl < 9; ++gl) {
    int L0 = (gl == 0) ? 1 : 0;
    int KT = L0 ? 12 : 8;
    if (!L0)
      hipLaunchKernelGGL(shadow_k, dim3(13696), dim3(256), 0, stream, X, SHLO, SHHI);
    for (int p = 0; p < phases; ++p) {
      int len = (107 - p*W < W) ? (107 - p*W) : W;
      int t0f = p*W;
      int t0b = 106 - p*W;
      hipLaunchKernelGGL(gemm_proj_k, dim3(len*16, 3, 2), dim3(256), 0, stream,
                         X, SHLO, SHHI, seq, str, lp, table, L0, KT,
                         WIH + (size_t)gl*294912, BIAS + gl*768, XPW, len, t0f, t0b);
      hipLaunchKernelGGL(scan_k, dim3(128, 2), dim3(512), 0, stream,
                         XPW, WHH + (size_t)gl*98304, BHHN + gl*256, X, HST,
                         len, t0f, t0b, (p == 0) ? 1 : 0);
    }
  }
  hipLaunchKernelGGL(final_k, dim3(544), dim3(256), 0, stream, X, lw, lb, out);
}